// Round 14
// baseline (118.702 us; speedup 1.0000x reference)
//
#include <hip/hip_runtime.h>
#include <math.h>
#include <stdint.h>

#define B_ 4
#define S_ 2048
#define DM_ 1024
#define DK_ 128

static constexpr float SCALE = 0.08838834764831845f; // 1/sqrt(128)

typedef __attribute__((ext_vector_type(8))) short short8;
typedef __attribute__((ext_vector_type(4))) float f32x4;
typedef __attribute__((ext_vector_type(4))) unsigned short us4;

__device__ __forceinline__ unsigned enc_f32(float f){
  unsigned u = __float_as_uint(f);
  return (u & 0x80000000u) ? ~u : (u | 0x80000000u);
}
__device__ __forceinline__ float dec_f32(unsigned u){
  unsigned v = (u & 0x80000000u) ? (u & 0x7FFFFFFFu) : ~u;
  return __uint_as_float(v);
}
__device__ __forceinline__ float f4get(const float4& v, int i){
  switch(i){ case 0: return v.x; case 1: return v.y; case 2: return v.z; default: return v.w; }
}
__device__ __forceinline__ unsigned short bf16rne(float f){
  unsigned u = __float_as_uint(f);
  unsigned r = (u + 0x7FFFu + ((u>>16)&1u)) >> 16;
  return (unsigned short)r;
}
__device__ __forceinline__ float bf16tof(unsigned short h){
  return __uint_as_float((unsigned)h << 16);
}
// async global->LDS, 16B per lane; LDS dest = wave-uniform base + lane*16
__device__ __forceinline__ void gload16(const void* g, void* l){
  __builtin_amdgcn_global_load_lds(
      (const __attribute__((address_space(1))) void*)g,
      (__attribute__((address_space(3))) void*)l, 16, 0, 0);
}

// ---- init: column-max to enc(-inf) ----
__global__ __launch_bounds__(256) void init_kernel(unsigned* __restrict__ cmax){
  int i = blockIdx.x*256 + threadIdx.x;
  if(i < B_*S_) cmax[i] = 0x007FFFFFu; // enc(-INF)
}

// ---- W pre-convert: f32 [1024][128] -> bf16 hi/lo, pre-tiled [32 t][col][40] ----
__global__ __launch_bounds__(256) void wconv_kernel(
    const float* __restrict__ Wq, const float* __restrict__ Wk, const float* __restrict__ Wv,
    unsigned short* __restrict__ Wth, unsigned short* __restrict__ Wtl)
{
  const int t = blockIdx.x;       // k-tile 0..31
  const int which = blockIdx.y;   // 0..2
  const float* W = (which==0) ? Wq : ((which==1) ? Wk : Wv);
  const int tid = threadIdx.x;
  const size_t obase = ((size_t)which*32 + t)*5120;
  #pragma unroll
  for(int it=0; it<2; ++it){
    int idx = tid + 256*it;       // 0..511 -> (col, g)
    int col = idx & 127, g = idx >> 7;
    unsigned short hs[8], ls[8];
    #pragma unroll
    for(int j=0;j<8;j++){
      float f = W[(size_t)(t*32 + g*8 + j)*DK_ + col];
      unsigned short h = bf16rne(f);
      hs[j] = h;
      ls[j] = bf16rne(f - bf16tof(h));
    }
    size_t o = obase + (size_t)col*40 + g*8;
    *(us4*)&Wth[o]   = us4{hs[0],hs[1],hs[2],hs[3]};
    *(us4*)&Wth[o+4] = us4{hs[4],hs[5],hs[6],hs[7]};
    *(us4*)&Wtl[o]   = us4{ls[0],ls[1],ls[2],ls[3]};
    *(us4*)&Wtl[o+4] = us4{ls[4],ls[5],ls[6],ls[7]};
  }
}

// ---- QKV GEMM v7: bf16x3 MFMA, M=64 tile, 2x2 wave grid (24 MFMA / 12 ds_read per wave/tile) ----
__global__ __launch_bounds__(256) void qkv_mfma_kernel(
    const float* __restrict__ X,
    const unsigned short* __restrict__ Wth, const unsigned short* __restrict__ Wtl,
    unsigned short* __restrict__ Qh, unsigned short* __restrict__ Ql,
    unsigned short* __restrict__ Kh, unsigned short* __restrict__ Kl,
    unsigned short* __restrict__ Vth, unsigned short* __restrict__ Vtl)
{
  // carve (bytes): Ah[64][40] @0 (5120B as shorts? [64][40]x2B=5120B) | Al @5120
  //                Bh0 @10240 | Bl0 @20480 | Bh1 @30720 | Bl1 @40960   -> 50KB total
  __shared__ __align__(16) unsigned char smem[51200];
  unsigned short* Ah = (unsigned short*)smem;
  unsigned short* Al = (unsigned short*)(smem + 5120);
  const int tid = threadIdx.x;
  const int w = tid >> 6, lane = tid & 63;
  const int wr = w >> 1, wc = w & 1;              // wave grid 2(row) x 2(col)
  const int l15 = lane & 15, g = lane >> 4;
  const int which = blockIdx.y;
  const int m0 = blockIdx.x * 64;
  const unsigned char* Wh8 = (const unsigned char*)(Wth + (size_t)which*32*5120);
  const unsigned char* Wl8 = (const unsigned char*)(Wtl + (size_t)which*32*5120);

  // X staging coords: thread covers rows R and R+32, k-quad kq
  const int R = tid >> 3, kq = tid & 7;
  const float* Xg0 = X + (size_t)(m0 + R)*DM_ + kq*4;
  const float* Xg1 = Xg0 + (size_t)32*DM_;
  float4 xv0 = *reinterpret_cast<const float4*>(Xg0);   // tile 0
  float4 xv1 = *reinterpret_cast<const float4*>(Xg1);

  // prologue: B tile 0 -> buf0 (20 x 1KB granules split across 4 waves)
  #pragma unroll
  for(int ii=0; ii<5; ++ii){
    int i = w + 4*ii;
    const unsigned char* src = (i<10) ? (Wh8 + i*1024) : (Wl8 + (i-10)*1024);
    unsigned dst = (i<10) ? (10240u + i*1024u) : (20480u + (unsigned)(i-10)*1024u);
    gload16(src + lane*16, smem + dst);
  }

  f32x4 acc[2][4] = {{f32x4{0,0,0,0},f32x4{0,0,0,0},f32x4{0,0,0,0},f32x4{0,0,0,0}},
                     {f32x4{0,0,0,0},f32x4{0,0,0,0},f32x4{0,0,0,0},f32x4{0,0,0,0}}};
  int buf = 0;
  for(int t=0; t<32; ++t){
    __syncthreads();            // prev readers done; B gloads (cur buf) drained
    {  // write A tile t (hi/lo bf16) from the two prefetched float4s
      unsigned short h0=bf16rne(xv0.x), h1=bf16rne(xv0.y), h2=bf16rne(xv0.z), h3=bf16rne(xv0.w);
      *(us4*)&Ah[R*40 + kq*4] = us4{h0,h1,h2,h3};
      *(us4*)&Al[R*40 + kq*4] = us4{ bf16rne(xv0.x - bf16tof(h0)), bf16rne(xv0.y - bf16tof(h1)),
                                     bf16rne(xv0.z - bf16tof(h2)), bf16rne(xv0.w - bf16tof(h3)) };
      unsigned short k0=bf16rne(xv1.x), k1=bf16rne(xv1.y), k2=bf16rne(xv1.z), k3=bf16rne(xv1.w);
      *(us4*)&Ah[(R+32)*40 + kq*4] = us4{k0,k1,k2,k3};
      *(us4*)&Al[(R+32)*40 + kq*4] = us4{ bf16rne(xv1.x - bf16tof(k0)), bf16rne(xv1.y - bf16tof(k1)),
                                          bf16rne(xv1.z - bf16tof(k2)), bf16rne(xv1.w - bf16tof(k3)) };
    }
    __syncthreads();            // A visible
    if(t+1 < 32){               // issue next B tile + X reg prefetch
      const unsigned char* WhT = Wh8 + (size_t)(t+1)*10240;
      const unsigned char* WlT = Wl8 + (size_t)(t+1)*10240;
      unsigned bhN = (buf^1) ? 30720u : 10240u;
      unsigned blN = (buf^1) ? 40960u : 20480u;
      #pragma unroll
      for(int ii=0; ii<5; ++ii){
        int i = w + 4*ii;
        const unsigned char* src = (i<10) ? (WhT + i*1024) : (WlT + (i-10)*1024);
        unsigned dst = (i<10) ? (bhN + i*1024) : (blN + (unsigned)(i-10)*1024);
        gload16(src + lane*16, smem + dst);
      }
      xv0 = *reinterpret_cast<const float4*>(Xg0 + (t+1)*32);
      xv1 = *reinterpret_cast<const float4*>(Xg1 + (t+1)*32);
    }
    const unsigned short* Bhc = (const unsigned short*)(smem + (buf ? 30720 : 10240));
    const unsigned short* Blc = (const unsigned short*)(smem + (buf ? 40960 : 20480));
    short8 ah0 = *(const short8*)&Ah[(wr*32 + l15)*40 + g*8];
    short8 al0 = *(const short8*)&Al[(wr*32 + l15)*40 + g*8];
    short8 ah1 = *(const short8*)&Ah[(wr*32 + 16 + l15)*40 + g*8];
    short8 al1 = *(const short8*)&Al[(wr*32 + 16 + l15)*40 + g*8];
    #pragma unroll
    for(int c=0;c<4;c++){
      int boff = ((wc*64 + c*16) + l15)*40 + g*8;
      short8 bh = *(const short8*)&Bhc[boff];
      short8 bl = *(const short8*)&Blc[boff];
      acc[0][c] = __builtin_amdgcn_mfma_f32_16x16x32_bf16(ah0, bh, acc[0][c], 0, 0, 0);
      acc[0][c] = __builtin_amdgcn_mfma_f32_16x16x32_bf16(ah0, bl, acc[0][c], 0, 0, 0);
      acc[0][c] = __builtin_amdgcn_mfma_f32_16x16x32_bf16(al0, bh, acc[0][c], 0, 0, 0);
      acc[1][c] = __builtin_amdgcn_mfma_f32_16x16x32_bf16(ah1, bh, acc[1][c], 0, 0, 0);
      acc[1][c] = __builtin_amdgcn_mfma_f32_16x16x32_bf16(ah1, bl, acc[1][c], 0, 0, 0);
      acc[1][c] = __builtin_amdgcn_mfma_f32_16x16x32_bf16(al1, bh, acc[1][c], 0, 0, 0);
    }
    buf ^= 1;
  }
  // epilogue: C layout col=lane&15, row=(lane>>4)*4+reg  [verified m89/m91]
  const int b = m0 >> 11;
  const int orow0 = g*4;
  if(which != 2){
    unsigned short* Oh = (which==0) ? Qh : Kh;
    unsigned short* Ol = (which==0) ? Ql : Kl;
    #pragma unroll
    for(int fr=0;fr<2;fr++){
      #pragma unroll
      for(int c=0;c<4;c++){
        int col = wc*64 + c*16 + l15;
        #pragma unroll
        for(int j=0;j<4;j++){
          float f = acc[fr][c][j];
          unsigned short h = bf16rne(f);
          unsigned short lo = bf16rne(f - bf16tof(h));
          size_t o = (size_t)(m0 + wr*32 + fr*16 + orow0 + j)*DK_ + col;
          Oh[o] = h; Ol[o] = lo;
        }
      }
    }
  } else {
    // V: two 32-row halves, transpose through LDS Tmp[32][133], store bf16 hi/lo Vt[b][d][s]
    float* Tmp = (float*)smem;                 // 17KB
    const int s0 = m0 & (S_-1);
    #pragma unroll
    for(int hr=0; hr<2; ++hr){
      __syncthreads();                         // prior smem readers/writers done
      if(wr == hr){
        #pragma unroll
        for(int fr=0;fr<2;fr++){
          #pragma unroll
          for(int c=0;c<4;c++){
            int col = wc*64 + c*16 + l15;
            #pragma unroll
            for(int j=0;j<4;j++)
              Tmp[(fr*16 + orow0 + j)*133 + col] = acc[fr][c][j];
          }
        }
      }
      __syncthreads();
      #pragma unroll
      for(int l2=0;l2<16;l2++){
        int p = tid + 256*l2;                  // 4096 elems: 128 d x 32 rows
        int d = p >> 5, rr = p & 31;
        float f = Tmp[rr*133 + d];
        unsigned short h = bf16rne(f);
        Vth[(size_t)(b*DK_ + d)*S_ + s0 + hr*32 + rr] = h;
        Vtl[(size_t)(b*DK_ + d)*S_ + s0 + hr*32 + rr] = bf16rne(f - bf16tof(h));
      }
    }
  }
}

// ---- scores via bf16x3 MFMA: raw s (masked=0) -> attn; column max ----
__global__ __launch_bounds__(256) void scores_kernel(
    const unsigned short* __restrict__ Qh, const unsigned short* __restrict__ Ql,
    const unsigned short* __restrict__ Kh, const unsigned short* __restrict__ Kl,
    float* __restrict__ attn, unsigned* __restrict__ cmax)
{
  const int tj = blockIdx.x, ti = blockIdx.y, b = blockIdx.z;
  const int tid = threadIdx.x;
  const int q0 = ti*64, k0 = tj*64;
  if(tj > ti){                                 // upper triangle: zero-fill tile
    float4 z = {0.f,0.f,0.f,0.f};
    #pragma unroll
    for(int l=0;l<4;l++){
      int p = tid + 256*l;
      int r = p >> 4, c = (p & 15) << 2;
      *reinterpret_cast<float4*>(&attn[((size_t)(b*S_) + q0 + r)*S_ + k0 + c]) = z;
    }
    return;
  }
  __shared__ __align__(16) unsigned short sm[18432];   // 4 x [64][72]
  __shared__ float cred[16][64];
  unsigned short* Qhs = sm;
  unsigned short* Qls = sm + 4608;
  unsigned short* Khs = sm + 9216;
  unsigned short* Kls = sm + 13824;
  const int w = tid >> 6, lane = tid & 63, l15 = lane & 15, g = lane >> 4;
  f32x4 acc[4] = {f32x4{0,0,0,0},f32x4{0,0,0,0},f32x4{0,0,0,0},f32x4{0,0,0,0}};
  for(int kh=0; kh<2; ++kh){
    __syncthreads();                           // prev compute readers done
    #pragma unroll
    for(int l=0;l<2;l++){                      // stage 4 tiles (this K-half)
      int p = tid + 256*l;
      int row = p >> 3, cc = p & 7;
      size_t gq = (size_t)(b*S_ + q0 + row)*DK_ + kh*64 + cc*8;
      size_t gk = (size_t)(b*S_ + k0 + row)*DK_ + kh*64 + cc*8;
      int lo_ = row*72 + cc*8;
      *(short8*)&Qhs[lo_] = *(const short8*)&Qh[gq];
      *(short8*)&Qls[lo_] = *(const short8*)&Ql[gq];
      *(short8*)&Khs[lo_] = *(const short8*)&Kh[gk];
      *(short8*)&Kls[lo_] = *(const short8*)&Kl[gk];
    }
    __syncthreads();
    #pragma unroll
    for(int ks=0; ks<2; ++ks){                 // 2 x K=32 per half
      int ao = (w*16 + l15)*72 + ks*32 + g*8;
      short8 ah = *(const short8*)&Qhs[ao];
      short8 al = *(const short8*)&Qls[ao];
      #pragma unroll
      for(int c=0;c<4;c++){
        int bo = (c*16 + l15)*72 + ks*32 + g*8;
        short8 bh = *(const short8*)&Khs[bo];
        short8 bl = *(const short8*)&Kls[bo];
        acc[c] = __builtin_amdgcn_mfma_f32_16x16x32_bf16(ah, bh, acc[c], 0, 0, 0);
        acc[c] = __builtin_amdgcn_mfma_f32_16x16x32_bf16(ah, bl, acc[c], 0, 0, 0);
        acc[c] = __builtin_amdgcn_mfma_f32_16x16x32_bf16(al, bh, acc[c], 0, 0, 0);
      }
    }
  }
  const bool full = (ti > tj);
  const int qbase = q0 + w*16 + g*4;
  #pragma unroll
  for(int c=0;c<4;c++){
    int kcol = k0 + c*16 + l15;
    float cm = -INFINITY;
    #pragma unroll
    for(int j=0;j<4;j++){
      int q = qbase + j;
      float s = acc[c][j]*SCALE;
      bool valid = full || (q >= kcol);
      attn[((size_t)(b*S_) + q)*S_ + kcol] = valid ? s : 0.f;
      if(valid) cm = fmaxf(cm, s);
    }
    cred[w*4 + g][c*16 + l15] = cm;
  }
  __syncthreads();
  if(tid < 64){
    float m = cred[0][tid];
    #pragma unroll
    for(int gg=1;gg<16;gg++) m = fmaxf(m, cred[gg][tid]);
    atomicMax(&cmax[b*S_ + k0 + tid], enc_f32(m));
  }
}

// ---- exp + per-column partial sums (READ-ONLY: no store; pv recomputes p) ----
__global__ __launch_bounds__(256) void expsum_kernel(
    const float* __restrict__ attn, const unsigned* __restrict__ cmax,
    float* __restrict__ colpart)
{
  const int cj = blockIdx.x, ti = blockIdx.y, b = blockIdx.z;
  if(ti < 4*cj) return;                        // fully masked block
  __shared__ float part[4][256];
  const int tid = threadIdx.x;
  const int c4 = tid & 63, g = tid >> 6;
  const int q0 = ti*64, k0 = cj*256;
  const int kbase = k0 + c4*4;
  float mc[4];
  #pragma unroll
  for(int j=0;j<4;j++) mc[j] = dec_f32(cmax[b*S_ + kbase + j]);
  float sum[4] = {0.f,0.f,0.f,0.f};
  #pragma unroll 4
  for(int rr=0;rr<16;rr++){
    int q = q0 + g*16 + rr;
    size_t idx = ((size_t)(b*S_) + q)*S_ + kbase;
    float4 sv = *reinterpret_cast<const float4*>(&attn[idx]);
    sum[0] += (q >= kbase+0) ? __expf(sv.x - mc[0]) : 0.f;
    sum[1] += (q >= kbase+1) ? __expf(sv.y - mc[1]) : 0.f;
    sum[2] += (q >= kbase+2) ? __expf(sv.z - mc[2]) : 0.f;
    sum[3] += (q >= kbase+3) ? __expf(sv.w - mc[3]) : 0.f;
  }
  #pragma unroll
  for(int j=0;j<4;j++) part[g][c4*4+j] = sum[j];
  __syncthreads();
  {
    int k = k0 + tid;
    float tot = ((part[0][tid] + part[1][tid]) + part[2][tid]) + part[3][tid];
    colpart[((size_t)(b*S_) + k)*32 + ti] = tot;
  }
}

// ---- column reduce in fixed order -> reciprocal sums ----
__global__ __launch_bounds__(256) void colreduce_kernel(
    const float* __restrict__ colpart, float* __restrict__ rcol)
{
  int i = blockIdx.x*256 + threadIdx.x;  // 0..8191 = b*S + k
  if(i >= B_*S_) return;
  int k = i & (S_-1);
  int t0 = k >> 6;
  float s = 0.f;
  for(int t=t0; t<32; t++) s += colpart[(size_t)i*32 + t];
  rcol[i] = 1.0f / s;
}

// ---- fused PV (bf16x3 MFMA): p=exp(s-m)*rcol written to attn in place; partials out ----
__global__ __launch_bounds__(256) void pv_kernel(
    float* __restrict__ attn, const unsigned* __restrict__ cmax,
    const float* __restrict__ rcol,
    const unsigned short* __restrict__ Vth, const unsigned short* __restrict__ Vtl,
    float* __restrict__ part, int ns)
{
  __shared__ __align__(16) unsigned short sm[27648];  // Ah,Al [64][72]; Vh,Vl [128][72] = 54KB
  unsigned short* Ahs = sm;
  unsigned short* Als = sm + 4608;
  unsigned short* Vhs = sm + 9216;
  unsigned short* Vls = sm + 18432;
  const int b = blockIdx.z, tid = threadIdx.x;
  const int sp = blockIdx.y;
  const int w = tid >> 6, lane = tid & 63, l15 = lane & 15, g = lane >> 4;
  const int t = 31 - (int)blockIdx.x;              // heavy tiles first
  const int q0 = t*64;
  const int nch = t + 1;
  const int lo = (sp*nch)/ns, hi = ((sp+1)*nch)/ns;
  f32x4 acc[8] = {f32x4{0,0,0,0},f32x4{0,0,0,0},f32x4{0,0,0,0},f32x4{0,0,0,0},
                  f32x4{0,0,0,0},f32x4{0,0,0,0},f32x4{0,0,0,0},f32x4{0,0,0,0}};
  const int er = tid >> 4, ekq = (tid & 15) << 2;  // E quad: rows rr*16+er, cols ekq..+3
  for(int ch=lo; ch<hi; ++ch){
    const int k0c = ch*64;
    uint4 mu = *reinterpret_cast<const uint4*>(&cmax[b*S_ + k0c + ekq]);
    float4 r4 = *reinterpret_cast<const float4*>(&rcol[b*S_ + k0c + ekq]);
    float mc0 = dec_f32(mu.x), mc1 = dec_f32(mu.y), mc2 = dec_f32(mu.z), mc3 = dec_f32(mu.w);
    const bool diag = (ch == t);
    __syncthreads();                               // prev MFMA readers done
    #pragma unroll
    for(int rr=0; rr<4; ++rr){
      int row = rr*16 + er;
      size_t ea = ((size_t)(b*S_) + q0 + row)*S_ + k0c + ekq;
      float4 sv = *reinterpret_cast<const float4*>(&attn[ea]);
      float p0 = __expf(sv.x - mc0)*r4.x;
      float p1 = __expf(sv.y - mc1)*r4.y;
      float p2 = __expf(sv.z - mc2)*r4.z;
      float p3 = __expf(sv.w - mc3)*r4.w;
      if(diag){                                    // q>=k  <=>  row>=kc (q0==k0c)
        p0 = (row >= ekq+0) ? p0 : 0.f;
        p1 = (row >= ekq+1) ? p1 : 0.f;
        p2 = (row >= ekq+2) ? p2 : 0.f;
        p3 = (row >= ekq+3) ? p3 : 0.f;
      }
      float4 pv4 = {p0,p1,p2,p3};
      *reinterpret_cast<float4*>(&attn[ea]) = pv4; // normalized attention (final output)
      unsigned short h0=bf16rne(p0), h1=bf16rne(p1), h2=bf16rne(p2), h3=bf16rne(p3);
      *(us4*)&Ahs[row*72 + ekq] = us4{h0,h1,h2,h3};
      *(us4*)&Als[row*72 + ekq] = us4{ bf16rne(p0-bf16tof(h0)), bf16rne(p1-bf16tof(h1)),
                                       bf16rne(p2-bf16tof(h2)), bf16rne(p3-bf16tof(h3)) };
    }
    #pragma unroll
    for(int v=0; v<4; ++v){                        // V stage: [128 d][64 k] hi/lo (1024 chunks)
      int idx = v*256 + tid;
      int d = idx >> 3, c8 = (idx & 7) << 3;
      size_t ga = (size_t)(b*DK_ + d)*S_ + k0c + c8;
      *(short8*)&Vhs[d*72 + c8] = *(const short8*)&Vth[ga];
      *(short8*)&Vls[d*72 + c8] = *(const short8*)&Vtl[ga];
    }
    __syncthreads();
    #pragma unroll
    for(int ks=0; ks<2; ++ks){
      int ao = (w*16 + l15)*72 + ks*32 + g*8;
      short8 ah = *(const short8*)&Ahs[ao];
      short8 al = *(const short8*)&Als[ao];
      #pragma unroll
      for(int c=0;c<8;c++){
        int bo = (c*16 + l15)*72 + ks*32 + g*8;
        short8 bh = *(const short8*)&Vhs[bo];
        short8 bl = *(const short8*)&Vls[bo];
        acc[c] = __builtin_amdgcn_mfma_f32_16x16x32_bf16(ah, bh, acc[c], 0, 0, 0);
        acc[c] = __builtin_amdgcn_mfma_f32_16x16x32_bf16(ah, bl, acc[c], 0, 0, 0);
        acc[c] = __builtin_amdgcn_mfma_f32_16x16x32_bf16(al, bh, acc[c], 0, 0, 0);
      }
    }
  }
  float* pout = part + (((size_t)(sp*B_ + b))*S_ + q0)*DK_;   // 64 x 128 region
  #pragma unroll
  for(int c=0;c<8;c++){
    #pragma unroll
    for(int j=0;j<4;j++){
      int qrow = w*16 + g*4 + j;
      pout[(size_t)qrow*DK_ + c*16 + l15] = acc[c][j];
    }
  }
}

// ---- sum split-K partials in fixed order ----
__global__ __launch_bounds__(256) void pvreduce_kernel(
    const float* __restrict__ part, float* __restrict__ out, int ns)
{
  const int N4 = (B_*S_*DK_)/4;   // 262144 float4
  int i = blockIdx.x*256 + threadIdx.x;
  if(i >= N4) return;
  const float4* p = reinterpret_cast<const float4*>(part);
  float4 a = p[i];
  for(int s=1; s<ns; ++s){
    float4 q = p[(size_t)s*N4 + i];
    a.x += q.x; a.y += q.y; a.z += q.z; a.w += q.w;
  }
  reinterpret_cast<float4*>(out)[i] = a;
}

extern "C" void kernel_launch(void* const* d_in, const int* in_sizes, int n_in,
                              void* d_out, int out_size, void* d_ws, size_t ws_size,
                              hipStream_t stream)
{
  (void)in_sizes; (void)n_in; (void)out_size;
  const float* X  = (const float*)d_in[0];
  const float* Wq = (const float*)d_in[1];
  const float* Wk = (const float*)d_in[2];
  const float* Wv = (const float*)d_in[3];
  float* out  = (float*)d_out;
  float* attn = out + (size_t)B_*S_*DK_;            // attention output region

  float* ws = (float*)d_ws;
  unsigned* cmax = (unsigned*)ws;                    // [8192]
  float* rcol    = ws + 8192;                        // [8192]
  float* colpart = ws + 16384;                       // [262144]
  unsigned short* Wth = (unsigned short*)(ws + 278528);   // [3][32][5120] shorts
  unsigned short* Wtl = (unsigned short*)(ws + 524288);
  unsigned short* Qh  = (unsigned short*)(ws + 770048);   // [8192][128] shorts each
  unsigned short* Ql  = (unsigned short*)(ws + 1294336);
  unsigned short* Kh  = (unsigned short*)(ws + 1818624);
  unsigned short* Kl  = (unsigned short*)(ws + 2342912);
  unsigned short* Vth = (unsigned short*)(ws + 2867200);  // [4][128][2048] shorts each
  unsigned short* Vtl = (unsigned short*)(ws + 3391488);
  const size_t base = 3915776;                       // floats used so far
  float* part    = ws + base;                        // [ns][4][2048][128]

  int ns = 4;
  if(ws_size < (base + (size_t)4*1048576)*sizeof(float)) ns = 2;
  if(ws_size < (base + (size_t)2*1048576)*sizeof(float)) ns = 1;

  init_kernel<<<dim3(32), dim3(256), 0, stream>>>(cmax);
  wconv_kernel<<<dim3(32,3), dim3(256), 0, stream>>>(Wq, Wk, Wv, Wth, Wtl);
  qkv_mfma_kernel<<<dim3(128,3), dim3(256), 0, stream>>>(X, Wth, Wtl, Qh, Ql, Kh, Kl, Vth, Vtl);
  scores_kernel<<<dim3(32,32,4), dim3(256), 0, stream>>>(Qh, Ql, Kh, Kl, attn, cmax);
  expsum_kernel<<<dim3(8,32,4), dim3(256), 0, stream>>>(attn, cmax, colpart);
  colreduce_kernel<<<dim3(32), dim3(256), 0, stream>>>(colpart, rcol);
  pv_kernel<<<dim3(32,ns,4), dim3(256), 0, stream>>>(attn, cmax, rcol, Vth, Vtl, part, ns);
  pvreduce_kernel<<<dim3(1024), dim3(256), 0, stream>>>(part, out, ns);
}